// Round 4
// baseline (487.174 us; speedup 1.0000x reference)
//
#include <hip/hip_runtime.h>
#include <stdint.h>

#define NH 8
#define HD 48
#define CC 384
#define NN 4096
#define CK 384

typedef short short8 __attribute__((ext_vector_type(8)));
typedef float floatx4 __attribute__((ext_vector_type(4)));

__device__ inline unsigned short f32_to_bf16_bits(float f) {
    uint32_t u = __builtin_bit_cast(uint32_t, f);
    u = (u + 0x7FFFu + ((u >> 16) & 1u)) >> 16;
    return (unsigned short)u;
}
__device__ inline short8 load8(const unsigned short* p) {
    return *reinterpret_cast<const short8*>(p);
}
typedef __attribute__((address_space(1))) const void gvoid_t;
typedef __attribute__((address_space(3))) void lvoid_t;
__device__ inline void async16(const unsigned short* g, unsigned short* l) {
    __builtin_amdgcn_global_load_lds((gvoid_t*)g, (lvoid_t*)l, 16, 0, 0);
}

// ---------------- weight convert f32 -> bf16 ----------------
__global__ __launch_bounds__(256) void k_cvt(
    const float* __restrict__ src, unsigned short* __restrict__ dst, int n8)
{
    int i = blockIdx.x * 256 + threadIdx.x;
    if (i >= n8) return;
    const float* s = src + (size_t)i * 8;
    unsigned short t[8];
    #pragma unroll
    for (int j = 0; j < 8; ++j) t[j] = f32_to_bf16_bits(s[j]);
    *reinterpret_cast<short8*>(dst + (size_t)i * 8) = *reinterpret_cast<short8*>(t);
}

// ---------------- x transpose: [B][C][N] f32 -> [B*N][C] bf16 ----------------
__global__ __launch_bounds__(256) void k_tr(
    const float* __restrict__ x, unsigned short* __restrict__ xT)
{
    __shared__ unsigned short tile[64][72];
    int bx = blockIdx.x;
    int nt = bx & 63; int rest = bx >> 6; int ct = rest % 6; int b = rest / 6;
    int c0 = ct * 64, n0 = nt * 64;
    int t = threadIdx.x;
    int nl = t & 63, w = t >> 6;
    const float* xb = x + (size_t)b * CC * NN;
    #pragma unroll
    for (int i = 0; i < 4; ++i) {
        int cl = w * 16 + i * 4;
        unsigned short u[4];
        #pragma unroll
        for (int j = 0; j < 4; ++j)
            u[j] = f32_to_bf16_bits(xb[(size_t)(c0 + cl + j) * NN + n0 + nl]);
        *reinterpret_cast<uint2*>(&tile[nl][cl]) = *reinterpret_cast<uint2*>(u);
    }
    __syncthreads();
    #pragma unroll
    for (int it = 0; it < 2; ++it) {
        int v = it * 256 + t;
        int row = v >> 3, seg = v & 7;
        *reinterpret_cast<short8*>(xT + ((size_t)b * NN + n0 + row) * CK + c0 + seg * 8) =
            load8(&tile[row][seg * 8]);
    }
}

// ---------------- QKV GEMM (128x128x64, XCD-swizzled) ----------------
__global__ __launch_bounds__(256) void k_qkv(
    const unsigned short* __restrict__ A,
    const unsigned short* __restrict__ W,
    unsigned short* __restrict__ QK,
    unsigned short* __restrict__ Vt)
{
    __shared__ unsigned short smem[17408];
    unsigned short* As = smem;
    unsigned short* Ws = smem + 8192;
    int bx = blockIdx.x;
    // XCD swizzle: all 9 f-tiles of an m-tile land on the same XCD (bx%8)
    int xcd = bx & 7, idx = bx >> 3;
    int tm = xcd * 64 + idx / 9;
    int tf = idx % 9;
    int m0 = tm * 128, f0 = tf * 128;
    int tid = threadIdx.x, wid = tid >> 6, lane = tid & 63;
    int l15 = lane & 15, quad = lane >> 4;
    int wm = wid & 1, wn = wid >> 1;

    const unsigned short* Ab = A + (size_t)m0 * CK;
    const unsigned short* Wb = W + (size_t)f0 * CK;

    floatx4 acc[4][4] = {};

    for (int kk = 0; kk < 6; ++kk) {
        int k0 = kk * 64;
        #pragma unroll
        for (int i = 0; i < 4; ++i) {
            int c = i * 256 + tid;
            async16(Ab + (size_t)(c >> 3) * CK + k0 + (c & 7) * 8, As + (i * 256 + wid * 64) * 8);
            async16(Wb + (size_t)(c >> 3) * CK + k0 + (c & 7) * 8, Ws + (i * 256 + wid * 64) * 8);
        }
        __syncthreads();
        #pragma unroll
        for (int ks = 0; ks < 2; ++ks) {
            short8 a[4], bf[4];
            #pragma unroll
            for (int i = 0; i < 4; ++i)
                a[i] = load8(As + (wm * 64 + i * 16 + l15) * 64 + ks * 32 + quad * 8);
            #pragma unroll
            for (int j = 0; j < 4; ++j)
                bf[j] = load8(Ws + (wn * 64 + j * 16 + l15) * 64 + ks * 32 + quad * 8);
            #pragma unroll
            for (int i = 0; i < 4; ++i)
                #pragma unroll
                for (int j = 0; j < 4; ++j)
                    acc[i][j] = __builtin_amdgcn_mfma_f32_16x16x32_bf16(a[i], bf[j], acc[i][j], 0, 0, 0);
        }
        __syncthreads();
    }

    int b = m0 >> 12, nb = m0 & 4095;
    if (tf < 6) {
        #pragma unroll
        for (int i = 0; i < 4; ++i)
            #pragma unroll
            for (int j = 0; j < 4; ++j)
                #pragma unroll
                for (int r = 0; r < 4; ++r)
                    smem[(wm * 64 + i * 16 + quad * 4 + r) * 128 + wn * 64 + j * 16 + l15] =
                        f32_to_bf16_bits(acc[i][j][r]);
        __syncthreads();
        #pragma unroll
        for (int it = 0; it < 8; ++it) {
            int c = it * 256 + tid;
            int row = c >> 4, seg = c & 15;
            *reinterpret_cast<short8*>(QK + (size_t)(m0 + row) * 768 + f0 + seg * 8) =
                load8(smem + row * 128 + seg * 8);
        }
    } else {
        #pragma unroll
        for (int i = 0; i < 4; ++i)
            #pragma unroll
            for (int j = 0; j < 4; ++j)
                #pragma unroll
                for (int r = 0; r < 4; ++r)
                    smem[(wn * 64 + j * 16 + l15) * 136 + wm * 64 + i * 16 + quad * 4 + r] =
                        f32_to_bf16_bits(acc[i][j][r]);
        __syncthreads();
        int fvb = (tf - 6) * 128;
        #pragma unroll
        for (int it = 0; it < 8; ++it) {
            int c = it * 256 + tid;
            int fl = c >> 4, seg = c & 15;
            int fv = fvb + fl;
            int h = fv / 48, d = fv - h * 48;
            *reinterpret_cast<short8*>(Vt + (((size_t)(b * 8 + h) * 48 + d) << 12) + nb + seg * 8) =
                load8(smem + fl * 136 + seg * 8);
        }
    }
}

// ---------------- fused attention + projection ----------------
// one block per (b, 64-token chunk); 4 waves, wave w owns q-rows w*16..w*16+15
__global__ __launch_bounds__(256) void k_ap(
    const unsigned short* __restrict__ QK,     // [B*N][768] (Q | K)
    const unsigned short* __restrict__ Vt,     // [B][8][48][4096]
    const unsigned short* __restrict__ W2,     // [384][384] bf16
    const float* __restrict__ bias,            // [384] f32
    float* __restrict__ out)                   // [B][384][4096] f32
{
    __shared__ unsigned short kl[64][56];      // per-head K tile [key][d]
    __shared__ unsigned short vt[48][72];      // per-head V^T [d][key]
    __shared__ unsigned short ao[64][392];     // attn out rows [tok][cout-in], 784B stride

    int bx = blockIdx.x;
    int cn = bx & 63, b = bx >> 6;
    int n0 = cn * 64;
    int tid = threadIdx.x, wid = tid >> 6, lane = tid & 63;
    int l15 = lane & 15, quad = lane >> 4;
    bool hi = quad >= 2;
    size_t rowbase = (size_t)b * NN + n0;

    const float scale = 0.14433756729740643f;  // 48^-0.5
    const unsigned short* qrow = QK + (rowbase + wid * 16 + l15) * 768;
    int d1 = 32 + ((quad & 1) << 3);           // clamped second-chunk offset (32/40)
    short8 z8 = {};

    for (int h = 0; h < 8; ++h) {
        int h48 = h * 48;
        __syncthreads();   // previous head's kl/vt consumers done
        // stage K tile: 64 rows x 48 d (6 x 16B per row)
        for (int v = tid; v < 384; v += 256) {
            int r = v / 6, sg = v - r * 6;
            *reinterpret_cast<uint4*>(&kl[r][sg * 8]) =
                *reinterpret_cast<const uint4*>(QK + (rowbase + r) * 768 + 384 + h48 + sg * 8);
        }
        // stage V^T tile: 48 d-rows x 64 keys
        const unsigned short* vbase = Vt + (((size_t)(b * 8 + h) * 48) << 12) + n0;
        for (int v = tid; v < 384; v += 256) {
            int d = v >> 3, sg = v & 7;
            *reinterpret_cast<uint4*>(&vt[d][sg * 8]) =
                *reinterpret_cast<const uint4*>(vbase + ((size_t)d << 12) + sg * 8);
        }
        __syncthreads();

        // Q fragments (lane-private, global): B-operand, n = q = l15
        short8 qf0 = load8(qrow + h48 + quad * 8);
        short8 qf1 = load8(qrow + h48 + d1);
        if (hi) qf1 = z8;

        // S^T = K·Q^T : 4 key-tiles, C/D col = q, row = key
        floatx4 st[4];
        #pragma unroll
        for (int tk = 0; tk < 4; ++tk) {
            floatx4 s = {};
            short8 ka = load8(&kl[tk * 16 + l15][quad * 8]);
            s = __builtin_amdgcn_mfma_f32_16x16x32_bf16(ka, qf0, s, 0, 0, 0);
            short8 kb = load8(&kl[tk * 16 + l15][d1]);
            if (hi) kb = z8;
            s = __builtin_amdgcn_mfma_f32_16x16x32_bf16(kb, qf1, s, 0, 0, 0);
            st[tk] = s;
        }

        // softmax over keys (per q-column): per-lane 16 values + cross-quad reduce
        float mx = -1e30f;
        #pragma unroll
        for (int tk = 0; tk < 4; ++tk)
            #pragma unroll
            for (int r = 0; r < 4; ++r) {
                st[tk][r] *= scale;
                mx = fmaxf(mx, st[tk][r]);
            }
        mx = fmaxf(mx, __shfl_xor(mx, 16));
        mx = fmaxf(mx, __shfl_xor(mx, 32));
        float sum = 0.f;
        #pragma unroll
        for (int tk = 0; tk < 4; ++tk)
            #pragma unroll
            for (int r = 0; r < 4; ++r) {
                st[tk][r] = __expf(st[tk][r] - mx);
                sum += st[tk][r];
            }
        sum += __shfl_xor(sum, 16);
        sum += __shfl_xor(sum, 32);
        float inv = 1.0f / sum;
        #pragma unroll
        for (int tk = 0; tk < 4; ++tk)
            #pragma unroll
            for (int r = 0; r < 4; ++r)
                st[tk][r] *= inv;

        // P C-tiles -> B-frags via shfl: lane(l15,quad) needs P[q=l15][key=ks*32+quad*8+j]
        int idxA = ((quad & 1) << 5) + l15;
        int idxB = idxA + 16;
        short8 pfrag[2];
        #pragma unroll
        for (int ks = 0; ks < 2; ++ks) {
            unsigned short pb[8];
            #pragma unroll
            for (int r = 0; r < 4; ++r) {
                float a0 = __shfl(st[2 * ks + 0][r], idxA);
                float a1 = __shfl(st[2 * ks + 1][r], idxA);
                pb[r] = f32_to_bf16_bits(hi ? a1 : a0);
                float b0 = __shfl(st[2 * ks + 0][r], idxB);
                float b1 = __shfl(st[2 * ks + 1][r], idxB);
                pb[4 + r] = f32_to_bf16_bits(hi ? b1 : b0);
            }
            pfrag[ks] = *reinterpret_cast<short8*>(pb);
        }

        // O^T = V^T · P^T : 3 d-tiles; D col = q = l15, row = d
        #pragma unroll
        for (int td = 0; td < 3; ++td) {
            floatx4 o = {};
            short8 va0 = load8(&vt[td * 16 + l15][quad * 8]);
            short8 va1 = load8(&vt[td * 16 + l15][32 + quad * 8]);
            o = __builtin_amdgcn_mfma_f32_16x16x32_bf16(va0, pfrag[0], o, 0, 0, 0);
            o = __builtin_amdgcn_mfma_f32_16x16x32_bf16(va1, pfrag[1], o, 0, 0, 0);
            unsigned short ob[4];
            #pragma unroll
            for (int r = 0; r < 4; ++r) ob[r] = f32_to_bf16_bits(o[r]);
            *reinterpret_cast<uint2*>(&ao[wid * 16 + l15][h48 + td * 16 + quad * 4]) =
                *reinterpret_cast<uint2*>(ob);
        }
    }
    __syncthreads();

    // projection: per wave 16 tokens x 384 couts, K=384; W2 B-frags from global (L2)
    #pragma unroll
    for (int half = 0; half < 2; ++half) {
        floatx4 acc[12] = {};
        #pragma unroll
        for (int s = 0; s < 12; ++s) {
            short8 a = load8(&ao[wid * 16 + l15][s * 32 + quad * 8]);
            #pragma unroll
            for (int nt = 0; nt < 12; ++nt) {
                short8 bf = load8(W2 + (size_t)(half * 192 + nt * 16 + l15) * 384 + s * 32 + quad * 8);
                acc[nt] = __builtin_amdgcn_mfma_f32_16x16x32_bf16(a, bf, acc[nt], 0, 0, 0);
            }
        }
        #pragma unroll
        for (int nt = 0; nt < 12; ++nt) {
            int cout = half * 192 + nt * 16 + l15;
            float bv = bias[cout];
            float4 v;
            v.x = acc[nt][0] + bv; v.y = acc[nt][1] + bv;
            v.z = acc[nt][2] + bv; v.w = acc[nt][3] + bv;
            *reinterpret_cast<float4*>(
                out + (((size_t)(b * CC + cout)) << 12) + n0 + wid * 16 + quad * 4) = v;
        }
    }
}

extern "C" void kernel_launch(void* const* d_in, const int* in_sizes, int n_in,
                              void* d_out, int out_size, void* d_ws, size_t ws_size,
                              hipStream_t stream) {
    const float* x      = (const float*)d_in[0];
    const float* qkv_w  = (const float*)d_in[1];
    const float* proj_w = (const float*)d_in[2];
    const float* proj_b = (const float*)d_in[3];
    float* out = (float*)d_out;

    const size_t nX  = (size_t)16 * CC * NN;     // 25,165,824
    const size_t nW1 = (size_t)3 * CC * CC;      // 442,368
    const size_t nW2 = (size_t)CC * CC;          // 147,456

    unsigned short* xT  = (unsigned short*)d_ws;
    unsigned short* w1b = xT  + nX;
    unsigned short* w2b = w1b + nW1;
    unsigned short* QK  = w2b + nW2;             // [B*N][768]
    unsigned short* Vt  = QK  + (size_t)16 * NN * 768;

    k_tr  <<<dim3(16 * 6 * 64), dim3(256), 0, stream>>>(x, xT);
    k_cvt <<<dim3((int)(nW1 / 8 + 255) / 256), dim3(256), 0, stream>>>(qkv_w, w1b, (int)(nW1 / 8));
    k_cvt <<<dim3((int)(nW2 / 8 + 255) / 256), dim3(256), 0, stream>>>(proj_w, w2b, (int)(nW2 / 8));

    k_qkv <<<dim3(4608), dim3(256), 0, stream>>>(xT, w1b, QK, Vt);
    k_ap  <<<dim3(1024), dim3(256), 0, stream>>>(QK, Vt, w2b, proj_b, out);
}